// Round 17
// baseline (266.233 us; speedup 1.0000x reference)
//
#include <hip/hip_runtime.h>
#include <hip/hip_bf16.h>
#include <stdint.h>
#include <stddef.h>

typedef unsigned short u16;
typedef __attribute__((ext_vector_type(8))) short short8;   // 8 x bf16 MFMA A/B frag
typedef __attribute__((ext_vector_type(4))) short bfx4;     // 4 x bf16 (8B)
typedef __attribute__((ext_vector_type(4))) float f32x4;    // MFMA C/D frag
typedef __attribute__((ext_vector_type(4))) float f4;

constexpr int B_ = 2, S_ = 2048, D_ = 1024, H_ = 16;
constexpr size_t OUT_ELEMS = (size_t)B_ * S_ * D_;          // 4,194,304

__device__ __forceinline__ u16 f2bf(float f) {              // RNE f32 -> bf16
    union { float f; unsigned u; } v; v.f = f;
    unsigned r = 0x7FFFu + ((v.u >> 16) & 1u);
    return (u16)((v.u + r) >> 16);
}

// packed RNE f32x2 -> bf16x2 (single VALU op)
__device__ __forceinline__ unsigned cvtpk(float lo, float hi) {
    unsigned r;
    asm("v_cvt_pk_bf16_f32 %0, %1, %2" : "=v"(r) : "v"(lo), "v"(hi));
    return r;
}

// async global->LDS, 16B per lane. LDS dest must be linear (base + lane*16).
__device__ __forceinline__ void gload16(const void* g, void* l) {
    auto gg = reinterpret_cast<const __attribute__((address_space(1))) unsigned*>(
        reinterpret_cast<uintptr_t>(g));
    auto ll = reinterpret_cast<__attribute__((address_space(3))) unsigned*>(
        reinterpret_cast<uintptr_t>(l));
    __builtin_amdgcn_global_load_lds(gg, ll, 16, 0, 0);
}

#define VMWAIT(N) do { asm volatile("s_waitcnt vmcnt(" #N ")" ::: "memory"); } while (0)
#define LGKMWAIT0() do { asm volatile("s_waitcnt lgkmcnt(0)" ::: "memory"); } while (0)
__device__ __forceinline__ void barrier_() {
    __builtin_amdgcn_s_barrier();
    __builtin_amdgcn_sched_barrier(0);
}

// ---------------------------------------------------------------------------
// Weight cast+transpose: W [1024,1024] f32 -> Wt [N][K] bf16 (4 matrices, z)
// ---------------------------------------------------------------------------
__global__ __launch_bounds__(256) void wtrans_kernel(
    const float* __restrict__ W0, const float* __restrict__ W1,
    const float* __restrict__ W2, const float* __restrict__ W3,
    u16* __restrict__ T0, u16* __restrict__ T1, u16* __restrict__ T2, u16* __restrict__ T3)
{
    __shared__ __align__(16) u16 Ts[64][72];
    const float* W = blockIdx.z == 0 ? W0 : blockIdx.z == 1 ? W1 : blockIdx.z == 2 ? W2 : W3;
    u16*         T = blockIdx.z == 0 ? T0 : blockIdx.z == 1 ? T1 : blockIdx.z == 2 ? T2 : T3;
    const int t = threadIdx.x;
    const int r0 = blockIdx.y * 64, c0 = blockIdx.x * 64;
    const int row = t >> 2, qd = t & 3;

    const float* src = W + (size_t)(r0 + row) * 1024 + c0 + qd * 16;
    u16 tmp[16];
    #pragma unroll
    for (int j = 0; j < 16; j += 4) {
        f4 v = *(const f4*)(src + j);
        tmp[j] = f2bf(v[0]); tmp[j+1] = f2bf(v[1]); tmp[j+2] = f2bf(v[2]); tmp[j+3] = f2bf(v[3]);
    }
    #pragma unroll
    for (int j = 0; j < 16; j++) Ts[row][qd * 16 + j] = tmp[j];
    __syncthreads();
    short8 o0, o1;
    #pragma unroll
    for (int j = 0; j < 8; j++) { o0[j] = (short)Ts[qd*16 + j][row]; o1[j] = (short)Ts[qd*16 + 8 + j][row]; }
    u16* dst = T + (size_t)(c0 + row) * 1024 + r0 + qd * 16;
    *(short8*)dst = o0;
    *(short8*)(dst + 8) = o1;
}

// ---------------------------------------------------------------------------
// Per-head V transpose: vp [B,S,D] bf16 -> vt [B*H][64][S] bf16 (coalesced)
// ---------------------------------------------------------------------------
__global__ __launch_bounds__(256) void vtrans_kernel(const u16* __restrict__ vp, u16* __restrict__ vt)
{
    __shared__ __align__(16) u16 Vs[64][72];
    const int t = threadIdx.x;
    const int s0 = blockIdx.x * 64;
    const int bh = blockIdx.y, b = bh >> 4, h = bh & 15;
    #pragma unroll
    for (int i = 0; i < 2; i++) {
        int c = t + 256 * i, row = c >> 3, ch = c & 7;
        *(short8*)(&Vs[row][ch * 8]) =
            *(const short8*)(vp + ((size_t)b * S_ + s0 + row) * D_ + h * 64 + ch * 8);
    }
    __syncthreads();
    #pragma unroll
    for (int i = 0; i < 2; i++) {
        int c = t + 256 * i, d = c >> 3, ch = c & 7;
        short8 o;
        #pragma unroll
        for (int j = 0; j < 8; j++) o[j] = (short)Vs[ch * 8 + j][d];
        *(short8*)(vt + ((size_t)bh * 64 + d) * S_ + s0 + ch * 8) = o;
    }
}

// ---------------------------------------------------------------------------
// Fused QKV projection GEMM (R12): f32 A, cast fused via cvtpk into staging.
// ---------------------------------------------------------------------------
struct StageF { f4 v[4]; };                         // raw f32, converted at store

__device__ __forceinline__ void a_load(StageF& st, const float* Af, int row0, int k0, int t) {
    const int row = t >> 1, half = t & 1;
    const float* p = Af + (size_t)(row0 + row) * D_ + k0 + half * 16;
    st.v[0] = *(const f4*)(p);
    st.v[1] = *(const f4*)(p + 4);
    st.v[2] = *(const f4*)(p + 8);
    st.v[3] = *(const f4*)(p + 12);
}

__device__ __forceinline__ void a_store(const StageF& st, u16* Ls, int t) {
    const int row = t >> 1, half = t & 1;
    union { unsigned u[4]; short8 s8; } h0, h1;
    h0.u[0] = cvtpk(st.v[0][0], st.v[0][1]); h0.u[1] = cvtpk(st.v[0][2], st.v[0][3]);
    h0.u[2] = cvtpk(st.v[1][0], st.v[1][1]); h0.u[3] = cvtpk(st.v[1][2], st.v[1][3]);
    h1.u[0] = cvtpk(st.v[2][0], st.v[2][1]); h1.u[1] = cvtpk(st.v[2][2], st.v[2][3]);
    h1.u[2] = cvtpk(st.v[3][0], st.v[3][1]); h1.u[3] = cvtpk(st.v[3][2], st.v[3][3]);
    const int sw = (row & 3) << 4;
    *(short8*)((char*)Ls + row * 64 + ((half * 32) ^ sw))      = h0.s8;
    *(short8*)((char*)Ls + row * 64 + ((half * 32 + 16) ^ sw)) = h1.s8;
}

__global__ __launch_bounds__(256, 3)
void gemm_qkvf(const float* __restrict__ A0, const float* __restrict__ A1, const float* __restrict__ A2,
               const u16* __restrict__ Bt0, const u16* __restrict__ Bt1, const u16* __restrict__ Bt2,
               const float* __restrict__ bi0, const float* __restrict__ bi1, const float* __restrict__ bi2,
               u16* __restrict__ Cq, u16* __restrict__ Ck, u16* __restrict__ Cv)
{
    constexpr int K = D_, N = D_;
    __shared__ __align__(16) u16 As[2][128 * 32];
    __shared__ __align__(16) u16 Bs[2][128 * 32];

    const int z = blockIdx.z;
    const float* Aptr = z == 0 ? A0  : z == 1 ? A1  : A2;
    const u16*   Bt   = z == 0 ? Bt0 : z == 1 ? Bt1 : Bt2;
    const float* bias = z == 0 ? bi0 : z == 1 ? bi1 : bi2;
    u16*         Cptr = z == 0 ? Cq  : z == 1 ? Ck  : Cv;
    const float scale = z == 0 ? 0.125f : 1.0f;     // q pre-scaled by 1/sqrt(64)

    const int t = threadIdx.x;
    const int w = t >> 6, l = t & 63, lr = l >> 4, lc = l & 15;
    const int wr = w >> 1, wc = w & 1;
    const int id = blockIdx.y * 8 + blockIdx.x;
    const int xcd = id & 7, i_ = id >> 3;
    const int row0 = ((xcd << 2) | ((i_ >> 4) << 1) | ((i_ >> 3) & 1)) * 128;
    const int col0 = (i_ & 7) * 128;
    const int NI = K >> 5;

    auto issueB = [&](int i, u16* dst) {
        #pragma unroll
        for (int j = 0; j < 2; j++) {
            int off = j * 256 + t;
            int row = off >> 2, ch = off & 3;
            const char* src = (const char*)Bt + (((size_t)(col0 + row) * K + i * 32) << 1)
                              + ((ch ^ (row & 3)) << 4);
            gload16(src, (char*)dst + off * 16);
        }
    };

    f32x4 acc[4][4] = {};
    StageF sa;
    issueB(0, Bs[0]);
    a_load(sa, Aptr, row0, 0, t);

    for (int i = 0; i < NI; i++) {
        const int p = i & 1;
        a_store(sa, As[p], t);                      // compiler vmcnt-waits A(i); drains B(i) too
        LGKMWAIT0();
        barrier_();
        if (i + 1 < NI) {
            issueB(i + 1, Bs[p ^ 1]);
            a_load(sa, Aptr, row0, (i + 1) * 32, t);
        }

        short8 af[4], bf_[4];
        #pragma unroll
        for (int mm = 0; mm < 4; mm++) {
            int r = wr * 64 + mm * 16 + lc;
            af[mm] = *(const short8*)((const char*)As[p] + r * 64 + ((lr * 16) ^ ((r & 3) << 4)));
        }
        #pragma unroll
        for (int nn = 0; nn < 4; nn++) {
            int r = wc * 64 + nn * 16 + lc;
            bf_[nn] = *(const short8*)((const char*)Bs[p] + r * 64 + ((lr * 16) ^ ((r & 3) << 4)));
        }
        #pragma unroll
        for (int mm = 0; mm < 4; mm++)
            #pragma unroll
            for (int nn = 0; nn < 4; nn++)
                acc[mm][nn] = __builtin_amdgcn_mfma_f32_16x16x32_bf16(af[mm], bf_[nn], acc[mm][nn], 0, 0, 0);
    }

    float bv[4];
    #pragma unroll
    for (int nn = 0; nn < 4; nn++) bv[nn] = bias[col0 + wc * 64 + nn * 16 + lc];

    #pragma unroll
    for (int mm = 0; mm < 4; mm++) {
        const int row = row0 + wr * 64 + mm * 16 + lr * 4;
        #pragma unroll
        for (int nn = 0; nn < 4; nn++) {
            const int col = col0 + wc * 64 + nn * 16 + lc;
            #pragma unroll
            for (int r = 0; r < 4; r++)
                Cptr[(size_t)(row + r) * N + col] = f2bf((acc[mm][nn][r] + bv[nn]) * scale);
        }
    }
}

// ---------------------------------------------------------------------------
// Out-projection GEMM (R8/R12 structure): all-bf16, counted-vmcnt pipeline.
// ---------------------------------------------------------------------------
__global__ __launch_bounds__(256, 3)
void gemm_out(const u16* __restrict__ Aptr, const u16* __restrict__ Bt,
              const float* __restrict__ bias, float* __restrict__ Cptr)
{
    constexpr int K = D_, N = D_;
    __shared__ __align__(16) u16 As[2][128 * 32];
    __shared__ __align__(16) u16 Bs[2][128 * 32];

    const int t = threadIdx.x;
    const int w = t >> 6, l = t & 63, lr = l >> 4, lc = l & 15;
    const int wr = w >> 1, wc = w & 1;
    const int id = blockIdx.y * 8 + blockIdx.x;
    const int xcd = id & 7, i_ = id >> 3;
    const int row0 = ((xcd << 2) | ((i_ >> 4) << 1) | ((i_ >> 3) & 1)) * 128;
    const int col0 = (i_ & 7) * 128;
    const int NI = K >> 5;

    auto issueT = [&](const u16* P, int r0_, int i, u16* dst) {
        #pragma unroll
        for (int j = 0; j < 2; j++) {
            int off = j * 256 + t;
            int row = off >> 2, ch = off & 3;
            const char* src = (const char*)P + (((size_t)(r0_ + row) * K + i * 32) << 1)
                              + ((ch ^ (row & 3)) << 4);
            gload16(src, (char*)dst + off * 16);
        }
    };

    f32x4 acc[4][4] = {};
    issueT(Bt, col0, 0, Bs[0]);
    issueT(Aptr, row0, 0, As[0]);

    for (int i = 0; i < NI; i++) {
        const int p = i & 1;
        if (i + 1 < NI) {
            issueT(Bt, col0, i + 1, Bs[p ^ 1]);
            issueT(Aptr, row0, i + 1, As[p ^ 1]);
            VMWAIT(4);
        } else {
            VMWAIT(0);
        }
        barrier_();

        short8 af[4], bf_[4];
        #pragma unroll
        for (int mm = 0; mm < 4; mm++) {
            int r = wr * 64 + mm * 16 + lc;
            af[mm] = *(const short8*)((const char*)As[p] + r * 64 + ((lr * 16) ^ ((r & 3) << 4)));
        }
        #pragma unroll
        for (int nn = 0; nn < 4; nn++) {
            int r = wc * 64 + nn * 16 + lc;
            bf_[nn] = *(const short8*)((const char*)Bs[p] + r * 64 + ((lr * 16) ^ ((r & 3) << 4)));
        }
        #pragma unroll
        for (int mm = 0; mm < 4; mm++)
            #pragma unroll
            for (int nn = 0; nn < 4; nn++)
                acc[mm][nn] = __builtin_amdgcn_mfma_f32_16x16x32_bf16(af[mm], bf_[nn], acc[mm][nn], 0, 0, 0);
        __builtin_amdgcn_s_barrier();
    }

    float bv[4];
    #pragma unroll
    for (int nn = 0; nn < 4; nn++) bv[nn] = bias[col0 + wc * 64 + nn * 16 + lc];

    #pragma unroll
    for (int mm = 0; mm < 4; mm++) {
        const int row = row0 + wr * 64 + mm * 16 + lr * 4;
        #pragma unroll
        for (int nn = 0; nn < 4; nn++) {
            const int col = col0 + wc * 64 + nn * 16 + lc;
            #pragma unroll
            for (int r = 0; r < 4; r++)
                Cptr[(size_t)(row + r) * N + col] = acc[mm][nn][r] + bv[nn];
        }
    }
}

// ---------------------------------------------------------------------------
// Fused attention (R15 pass 2) + BARRIER-FREE pass 1: each wave owns a
// 256-wide k-slice, streams K straight from L2 (no LDS, no barriers), 16
// independent MFMAs per 2 loads; wave partials -> 4KB LDS -> ONE barrier ->
// row sum. Pass-2 tile-0 K/V prefetch issued at kernel start (flies under
// all of pass 1). Pass 2: R15 verbatim (P LDS-transpose coalesced stores).
// ---------------------------------------------------------------------------
__global__ __launch_bounds__(512, 4)
void attn_kernel(const u16* __restrict__ qp, const u16* __restrict__ kp,
                 const u16* __restrict__ vt, float* __restrict__ Pout,
                 u16* __restrict__ xout)
{
    __shared__ __align__(16) u16 Ks[2][128 * 64];   // 32KB [k][d], source-swizzled
    __shared__ __align__(16) u16 Vts[2][64 * 128];  // 32KB [d][k] rows 256B, source-swizzled
    __shared__ __align__(16) float Pls[8][16][32];  // 16KB per-wave P transpose tiles (aliases Psum)

    const int t = threadIdx.x;
    const int w = t >> 6, l = t & 63, lr = l >> 4, lc = l & 15;
    // XCD-bijective swizzle: 512 blocks -> 8 chunks of 64 (= 4 bh each)
    const int bid = blockIdx.x;
    const int s = ((bid & 7) << 6) | (bid >> 3);
    const int q0 = (s & 15) * 128;
    const int bh = s >> 4, b = bh >> 4, h = bh & 15;
    const float L2E = 1.4426950408889634f;
    constexpr int NT = S_ / 128;                    // 16 tiles

    auto issueK = [&](int kt, int buf) {
        #pragma unroll
        for (int i = 0; i < 2; i++) {
            int off = i * 512 + t, row = off >> 3, ch = off & 7;
            const char* src = (const char*)kp + ((((size_t)b * S_ + kt * 128 + row) * D_ + h * 64) << 1)
                              + ((ch ^ (row & 7)) << 4);
            gload16(src, (char*)Ks[buf] + off * 16);
        }
    };
    auto issueV = [&](int kt, int buf) {
        #pragma unroll
        for (int i = 0; i < 2; i++) {
            int off = i * 512 + t, row = off >> 4, ch = off & 15;
            const char* src = (const char*)vt + ((((size_t)bh * 64 + row) * S_ + kt * 128) << 1)
                              + ((ch ^ (row & 7)) << 4);
            gload16(src, (char*)Vts[buf] + off * 16);
        }
    };

    // pass-2 Q frags (loaded first; L2-hot) and pass-2 tile-0 prefetch
    short8 qf[2];
    {
        const u16* qrow = qp + ((size_t)b * S_ + q0 + w * 16 + lc) * D_ + h * 64;
        qf[0] = *(const short8*)(qrow + lr * 8);
        qf[1] = *(const short8*)(qrow + 32 + lr * 8);
    }
    issueK(0, 0); issueV(0, 0);                     // fly under ALL of pass 1

    // ---------------- pass 1: barrier-free per-wave k-slice rowsum ----------------
    short8 qf1[8][2];
    #pragma unroll
    for (int qb = 0; qb < 8; qb++) {
        const u16* qrow = qp + ((size_t)b * S_ + q0 + qb * 16 + lc) * D_ + h * 64;
        qf1[qb][0] = *(const short8*)(qrow + lr * 8);
        qf1[qb][1] = *(const short8*)(qrow + 32 + lr * 8);
    }
    float psum[8] = {0.f, 0.f, 0.f, 0.f, 0.f, 0.f, 0.f, 0.f};
    #pragma unroll 2
    for (int kb = 0; kb < 16; kb++) {
        const u16* krow = kp + ((size_t)b * S_ + w * 256 + kb * 16 + lc) * D_ + h * 64;
        short8 kf0 = *(const short8*)(krow + lr * 8);
        short8 kf1 = *(const short8*)(krow + 32 + lr * 8);
        #pragma unroll
        for (int qb = 0; qb < 8; qb++) {
            f32x4 sacc = {};
            sacc = __builtin_amdgcn_mfma_f32_16x16x32_bf16(kf0, qf1[qb][0], sacc, 0, 0, 0);
            sacc = __builtin_amdgcn_mfma_f32_16x16x32_bf16(kf1, qf1[qb][1], sacc, 0, 0, 0);
            psum[qb] += exp2f(sacc[0] * L2E) + exp2f(sacc[1] * L2E)
                      + exp2f(sacc[2] * L2E) + exp2f(sacc[3] * L2E);
        }
    }
    #pragma unroll
    for (int qb = 0; qb < 8; qb++) {
        psum[qb] += __shfl_xor(psum[qb], 16);
        psum[qb] += __shfl_xor(psum[qb], 32);
    }
    float* Psum = &Pls[0][0][0];                    // 8 waves x 8 qb x 16 lc = 4KB
    if (l < 16) {
        #pragma unroll
        for (int qb = 0; qb < 8; qb++) Psum[(w * 8 + qb) * 16 + lc] = psum[qb];
    }
    __syncthreads();                                // ONE pass-1 barrier
    float sum = 0.f;
    #pragma unroll
    for (int wp = 0; wp < 8; wp++) sum += Psum[(wp * 8 + w) * 16 + lc];
    const float l2i = -log2f(sum);                  // row-uniform; folded into exponent

    // ---------------- pass 2: P -> LDS transpose -> coalesced Pout + in-register PV ----------------
    f32x4 xacc[4] = {};
    float* pls = &Pls[w][0][0];
    float* prow0 = Pout + ((size_t)bh * S_ + q0 + w * 16) * S_;

    for (int kt = 0; kt < NT; kt++) {
        const int p = kt & 1;
        if (kt + 1 < NT) { issueK(kt + 1, p ^ 1); issueV(kt + 1, p ^ 1); }
        // vmcnt queue (old->new): [loads(kt) 4 | stores(kt-1) 8 | loads(kt+1) 4]
        if (kt == 0)           VMWAIT(4);
        else if (kt + 1 < NT)  VMWAIT(12);
        else                   VMWAIT(8);
        barrier_();                                 // also orders Psum reads vs Pls writes (kt==0)
        const char* Kb = (const char*)Ks[p];
        const char* Vb = (const char*)Vts[p];

        #pragma unroll
        for (int kk = 0; kk < 4; kk++) {
            union { unsigned u[4]; short8 s8; } pu;
            #pragma unroll
            for (int fo = 0; fo < 2; fo++) {
                const int f = kk * 2 + fo;
                int r = f * 16 + lc, sw = (r & 7) << 4;
                const char* kb = Kb + r * 128;
                short8 k0 = *(const short8*)(kb + ((lr * 16) ^ sw));
                short8 k1 = *(const short8*)(kb + ((64 + lr * 16) ^ sw));
                f32x4 sacc = {};
                __builtin_amdgcn_s_setprio(1);
                sacc = __builtin_amdgcn_mfma_f32_16x16x32_bf16(k0, qf[0], sacc, 0, 0, 0);
                sacc = __builtin_amdgcn_mfma_f32_16x16x32_bf16(k1, qf[1], sacc, 0, 0, 0);
                __builtin_amdgcn_s_setprio(0);
                f32x4 pv_;
                pv_[0] = exp2f(fmaf(sacc[0], L2E, l2i));
                pv_[1] = exp2f(fmaf(sacc[1], L2E, l2i));
                pv_[2] = exp2f(fmaf(sacc[2], L2E, l2i));
                pv_[3] = exp2f(fmaf(sacc[3], L2E, l2i));
                // stage into per-wave transpose tile (row=lc, chunk=fo*4+lr, XOR-swizzled)
                *(f32x4*)((char*)pls + lc * 128 + (((fo * 64 + lr * 16)) ^ ((lc & 7) << 4))) = pv_;
                pu.u[fo * 2 + 0] = cvtpk(pv_[0], pv_[1]);
                pu.u[fo * 2 + 1] = cvtpk(pv_[2], pv_[3]);
            }
            // coalesced Pout store: 2 instructions x (8 rows x 128B full lines)
            {
                float* prow = prow0 + (size_t)kt * 128 + kk * 32;
                #pragma unroll
                for (int half = 0; half < 2; half++) {
                    int row = half * 8 + (l >> 3), chunk = l & 7;
                    f32x4 pr = *(const f32x4*)((const char*)pls + row * 128
                               + ((chunk * 16) ^ (((l >> 3) & 7) << 4)));
                    *(f32x4*)(prow + (size_t)row * S_ + chunk * 4) = pr;
                }
            }
            const short8 pa = pu.s8;   // A-frag: P[q=lc][k = kk*32 + perm(lr,j)]
            __builtin_amdgcn_s_setprio(1);
            #pragma unroll
            for (int n = 0; n < 4; n++) {
                int rr = n * 16 + lc, sw2 = (rr & 7) << 4;
                const char* vrow = Vb + rr * 256;
                union { bfx4 h[2]; short8 s8; } vu;
                vu.h[0] = *(const bfx4*)(vrow + ((kk * 64 + lr * 8) ^ sw2));
                vu.h[1] = *(const bfx4*)(vrow + ((kk * 64 + 32 + lr * 8) ^ sw2));
                xacc[n] = __builtin_amdgcn_mfma_f32_16x16x32_bf16(pa, vu.s8, xacc[n], 0, 0, 0);
            }
            __builtin_amdgcn_s_setprio(0);
        }
        __builtin_amdgcn_s_barrier();               // reads of buf p done before overwrite
    }

    #pragma unroll
    for (int n = 0; n < 4; n++) {
        #pragma unroll
        for (int r = 0; r < 4; r++) {
            int row = q0 + w * 16 + lr * 4 + r;
            int col = h * 64 + n * 16 + lc;
            xout[((size_t)b * S_ + row) * D_ + col] = f2bf(xacc[n][r]);
        }
    }
}

// ---------------------------------------------------------------------------
extern "C" void kernel_launch(void* const* d_in, const int* in_sizes, int n_in,
                              void* d_out, int out_size, void* d_ws, size_t ws_size,
                              hipStream_t stream)
{
    const float* qin = (const float*)d_in[0];
    const float* kin = (const float*)d_in[1];
    const float* vin = (const float*)d_in[2];
    const float* Wq  = (const float*)d_in[3];
    const float* bq  = (const float*)d_in[4];
    const float* Wk  = (const float*)d_in[5];
    const float* bk  = (const float*)d_in[6];
    const float* Wv  = (const float*)d_in[7];
    const float* bv  = (const float*)d_in[8];
    const float* Wo  = (const float*)d_in[9];
    const float* bo  = (const float*)d_in[10];

    // ws layout (u16 elements)
    u16* base = (u16*)d_ws;
    u16* Wqt = base;                    // 1M each
    u16* Wkt = base + 1048576;
    u16* Wvt = base + 2097152;
    u16* Wot = base + 3145728;
    u16* qpb = base + 4194304;          // 4M each
    u16* kpb = base + 8388608;
    u16* vpb = base + 12582912;
    u16* vtb = base + 16777216;         // vt[bh][64][2048]
    u16* xb  = base + 20971520;         // total ~50MB

    float* out  = (float*)d_out;
    float* Pout = out + OUT_ELEMS;

    wtrans_kernel<<<dim3(16, 16, 4), 256, 0, stream>>>(Wq, Wk, Wv, Wo, Wqt, Wkt, Wvt, Wot);
    gemm_qkvf<<<dim3(8, 32, 3), 256, 0, stream>>>(
        qin, kin, vin, Wqt, Wkt, Wvt, bq, bk, bv, qpb, kpb, vpb);
    vtrans_kernel<<<dim3(32, 32), 256, 0, stream>>>(vpb, vtb);
    attn_kernel<<<512, 512, 0, stream>>>(qpb, kpb, vtb, Pout, xb);
    gemm_out<<<dim3(8, 32), 256, 0, stream>>>(xb, Wot, bo, out);
}

// Round 18
// 257.661 us; speedup vs baseline: 1.0333x; 1.0333x over previous
//
#include <hip/hip_runtime.h>
#include <hip/hip_bf16.h>
#include <stdint.h>
#include <stddef.h>

typedef unsigned short u16;
typedef __attribute__((ext_vector_type(8))) short short8;   // 8 x bf16 MFMA A/B frag
typedef __attribute__((ext_vector_type(4))) short bfx4;     // 4 x bf16 (8B)
typedef __attribute__((ext_vector_type(4))) float f32x4;    // MFMA C/D frag
typedef __attribute__((ext_vector_type(4))) float f4;

constexpr int B_ = 2, S_ = 2048, D_ = 1024, H_ = 16;
constexpr size_t OUT_ELEMS = (size_t)B_ * S_ * D_;          // 4,194,304

__device__ __forceinline__ u16 f2bf(float f) {              // RNE f32 -> bf16
    union { float f; unsigned u; } v; v.f = f;
    unsigned r = 0x7FFFu + ((v.u >> 16) & 1u);
    return (u16)((v.u + r) >> 16);
}

// packed RNE f32x2 -> bf16x2 (single VALU op)
__device__ __forceinline__ unsigned cvtpk(float lo, float hi) {
    unsigned r;
    asm("v_cvt_pk_bf16_f32 %0, %1, %2" : "=v"(r) : "v"(lo), "v"(hi));
    return r;
}

// async global->LDS, 16B per lane. LDS dest must be linear (base + lane*16).
__device__ __forceinline__ void gload16(const void* g, void* l) {
    auto gg = reinterpret_cast<const __attribute__((address_space(1))) unsigned*>(
        reinterpret_cast<uintptr_t>(g));
    auto ll = reinterpret_cast<__attribute__((address_space(3))) unsigned*>(
        reinterpret_cast<uintptr_t>(l));
    __builtin_amdgcn_global_load_lds(gg, ll, 16, 0, 0);
}

#define VMWAIT(N) do { asm volatile("s_waitcnt vmcnt(" #N ")" ::: "memory"); } while (0)
#define LGKMWAIT0() do { asm volatile("s_waitcnt lgkmcnt(0)" ::: "memory"); } while (0)
__device__ __forceinline__ void barrier_() {
    __builtin_amdgcn_s_barrier();
    __builtin_amdgcn_sched_barrier(0);
}

// ---------------------------------------------------------------------------
// Weight cast+transpose: W [1024,1024] f32 -> Wt [N][K] bf16 (4 matrices, z)
// ---------------------------------------------------------------------------
__global__ __launch_bounds__(256) void wtrans_kernel(
    const float* __restrict__ W0, const float* __restrict__ W1,
    const float* __restrict__ W2, const float* __restrict__ W3,
    u16* __restrict__ T0, u16* __restrict__ T1, u16* __restrict__ T2, u16* __restrict__ T3)
{
    __shared__ __align__(16) u16 Ts[64][72];
    const float* W = blockIdx.z == 0 ? W0 : blockIdx.z == 1 ? W1 : blockIdx.z == 2 ? W2 : W3;
    u16*         T = blockIdx.z == 0 ? T0 : blockIdx.z == 1 ? T1 : blockIdx.z == 2 ? T2 : T3;
    const int t = threadIdx.x;
    const int r0 = blockIdx.y * 64, c0 = blockIdx.x * 64;
    const int row = t >> 2, qd = t & 3;

    const float* src = W + (size_t)(r0 + row) * 1024 + c0 + qd * 16;
    u16 tmp[16];
    #pragma unroll
    for (int j = 0; j < 16; j += 4) {
        f4 v = *(const f4*)(src + j);
        tmp[j] = f2bf(v[0]); tmp[j+1] = f2bf(v[1]); tmp[j+2] = f2bf(v[2]); tmp[j+3] = f2bf(v[3]);
    }
    #pragma unroll
    for (int j = 0; j < 16; j++) Ts[row][qd * 16 + j] = tmp[j];
    __syncthreads();
    short8 o0, o1;
    #pragma unroll
    for (int j = 0; j < 8; j++) { o0[j] = (short)Ts[qd*16 + j][row]; o1[j] = (short)Ts[qd*16 + 8 + j][row]; }
    u16* dst = T + (size_t)(c0 + row) * 1024 + r0 + qd * 16;
    *(short8*)dst = o0;
    *(short8*)(dst + 8) = o1;
}

// ---------------------------------------------------------------------------
// Per-head V transpose: vp [B,S,D] bf16 -> vt [B*H][64][S] bf16 (coalesced)
// ---------------------------------------------------------------------------
__global__ __launch_bounds__(256) void vtrans_kernel(const u16* __restrict__ vp, u16* __restrict__ vt)
{
    __shared__ __align__(16) u16 Vs[64][72];
    const int t = threadIdx.x;
    const int s0 = blockIdx.x * 64;
    const int bh = blockIdx.y, b = bh >> 4, h = bh & 15;
    #pragma unroll
    for (int i = 0; i < 2; i++) {
        int c = t + 256 * i, row = c >> 3, ch = c & 7;
        *(short8*)(&Vs[row][ch * 8]) =
            *(const short8*)(vp + ((size_t)b * S_ + s0 + row) * D_ + h * 64 + ch * 8);
    }
    __syncthreads();
    #pragma unroll
    for (int i = 0; i < 2; i++) {
        int c = t + 256 * i, d = c >> 3, ch = c & 7;
        short8 o;
        #pragma unroll
        for (int j = 0; j < 8; j++) o[j] = (short)Vs[ch * 8 + j][d];
        *(short8*)(vt + ((size_t)bh * 64 + d) * S_ + s0 + ch * 8) = o;
    }
}

// ---------------------------------------------------------------------------
// Fused QKV projection GEMM (R12): f32 A, cast fused via cvtpk into staging.
// ---------------------------------------------------------------------------
struct StageF { f4 v[4]; };                         // raw f32, converted at store

__device__ __forceinline__ void a_load(StageF& st, const float* Af, int row0, int k0, int t) {
    const int row = t >> 1, half = t & 1;
    const float* p = Af + (size_t)(row0 + row) * D_ + k0 + half * 16;
    st.v[0] = *(const f4*)(p);
    st.v[1] = *(const f4*)(p + 4);
    st.v[2] = *(const f4*)(p + 8);
    st.v[3] = *(const f4*)(p + 12);
}

__device__ __forceinline__ void a_store(const StageF& st, u16* Ls, int t) {
    const int row = t >> 1, half = t & 1;
    union { unsigned u[4]; short8 s8; } h0, h1;
    h0.u[0] = cvtpk(st.v[0][0], st.v[0][1]); h0.u[1] = cvtpk(st.v[0][2], st.v[0][3]);
    h0.u[2] = cvtpk(st.v[1][0], st.v[1][1]); h0.u[3] = cvtpk(st.v[1][2], st.v[1][3]);
    h1.u[0] = cvtpk(st.v[2][0], st.v[2][1]); h1.u[1] = cvtpk(st.v[2][2], st.v[2][3]);
    h1.u[2] = cvtpk(st.v[3][0], st.v[3][1]); h1.u[3] = cvtpk(st.v[3][2], st.v[3][3]);
    const int sw = (row & 3) << 4;
    *(short8*)((char*)Ls + row * 64 + ((half * 32) ^ sw))      = h0.s8;
    *(short8*)((char*)Ls + row * 64 + ((half * 32 + 16) ^ sw)) = h1.s8;
}

__global__ __launch_bounds__(256, 3)
void gemm_qkvf(const float* __restrict__ A0, const float* __restrict__ A1, const float* __restrict__ A2,
               const u16* __restrict__ Bt0, const u16* __restrict__ Bt1, const u16* __restrict__ Bt2,
               const float* __restrict__ bi0, const float* __restrict__ bi1, const float* __restrict__ bi2,
               u16* __restrict__ Cq, u16* __restrict__ Ck, u16* __restrict__ Cv)
{
    constexpr int K = D_, N = D_;
    __shared__ __align__(16) u16 As[2][128 * 32];
    __shared__ __align__(16) u16 Bs[2][128 * 32];

    const int z = blockIdx.z;
    const float* Aptr = z == 0 ? A0  : z == 1 ? A1  : A2;
    const u16*   Bt   = z == 0 ? Bt0 : z == 1 ? Bt1 : Bt2;
    const float* bias = z == 0 ? bi0 : z == 1 ? bi1 : bi2;
    u16*         Cptr = z == 0 ? Cq  : z == 1 ? Ck  : Cv;
    const float scale = z == 0 ? 0.125f : 1.0f;     // q pre-scaled by 1/sqrt(64)

    const int t = threadIdx.x;
    const int w = t >> 6, l = t & 63, lr = l >> 4, lc = l & 15;
    const int wr = w >> 1, wc = w & 1;
    const int id = blockIdx.y * 8 + blockIdx.x;
    const int xcd = id & 7, i_ = id >> 3;
    const int row0 = ((xcd << 2) | ((i_ >> 4) << 1) | ((i_ >> 3) & 1)) * 128;
    const int col0 = (i_ & 7) * 128;
    const int NI = K >> 5;

    auto issueB = [&](int i, u16* dst) {
        #pragma unroll
        for (int j = 0; j < 2; j++) {
            int off = j * 256 + t;
            int row = off >> 2, ch = off & 3;
            const char* src = (const char*)Bt + (((size_t)(col0 + row) * K + i * 32) << 1)
                              + ((ch ^ (row & 3)) << 4);
            gload16(src, (char*)dst + off * 16);
        }
    };

    f32x4 acc[4][4] = {};
    StageF sa;
    issueB(0, Bs[0]);
    a_load(sa, Aptr, row0, 0, t);

    for (int i = 0; i < NI; i++) {
        const int p = i & 1;
        a_store(sa, As[p], t);                      // compiler vmcnt-waits A(i); drains B(i) too
        LGKMWAIT0();
        barrier_();
        if (i + 1 < NI) {
            issueB(i + 1, Bs[p ^ 1]);
            a_load(sa, Aptr, row0, (i + 1) * 32, t);
        }

        short8 af[4], bf_[4];
        #pragma unroll
        for (int mm = 0; mm < 4; mm++) {
            int r = wr * 64 + mm * 16 + lc;
            af[mm] = *(const short8*)((const char*)As[p] + r * 64 + ((lr * 16) ^ ((r & 3) << 4)));
        }
        #pragma unroll
        for (int nn = 0; nn < 4; nn++) {
            int r = wc * 64 + nn * 16 + lc;
            bf_[nn] = *(const short8*)((const char*)Bs[p] + r * 64 + ((lr * 16) ^ ((r & 3) << 4)));
        }
        #pragma unroll
        for (int mm = 0; mm < 4; mm++)
            #pragma unroll
            for (int nn = 0; nn < 4; nn++)
                acc[mm][nn] = __builtin_amdgcn_mfma_f32_16x16x32_bf16(af[mm], bf_[nn], acc[mm][nn], 0, 0, 0);
    }

    float bv[4];
    #pragma unroll
    for (int nn = 0; nn < 4; nn++) bv[nn] = bias[col0 + wc * 64 + nn * 16 + lc];

    #pragma unroll
    for (int mm = 0; mm < 4; mm++) {
        const int row = row0 + wr * 64 + mm * 16 + lr * 4;
        #pragma unroll
        for (int nn = 0; nn < 4; nn++) {
            const int col = col0 + wc * 64 + nn * 16 + lc;
            #pragma unroll
            for (int r = 0; r < 4; r++)
                Cptr[(size_t)(row + r) * N + col] = f2bf((acc[mm][nn][r] + bv[nn]) * scale);
        }
    }
}

// ---------------------------------------------------------------------------
// Out-projection GEMM (R8/R12 structure): all-bf16, counted-vmcnt pipeline.
// ---------------------------------------------------------------------------
__global__ __launch_bounds__(256, 3)
void gemm_out(const u16* __restrict__ Aptr, const u16* __restrict__ Bt,
              const float* __restrict__ bias, float* __restrict__ Cptr)
{
    constexpr int K = D_, N = D_;
    __shared__ __align__(16) u16 As[2][128 * 32];
    __shared__ __align__(16) u16 Bs[2][128 * 32];

    const int t = threadIdx.x;
    const int w = t >> 6, l = t & 63, lr = l >> 4, lc = l & 15;
    const int wr = w >> 1, wc = w & 1;
    const int id = blockIdx.y * 8 + blockIdx.x;
    const int xcd = id & 7, i_ = id >> 3;
    const int row0 = ((xcd << 2) | ((i_ >> 4) << 1) | ((i_ >> 3) & 1)) * 128;
    const int col0 = (i_ & 7) * 128;
    const int NI = K >> 5;

    auto issueT = [&](const u16* P, int r0_, int i, u16* dst) {
        #pragma unroll
        for (int j = 0; j < 2; j++) {
            int off = j * 256 + t;
            int row = off >> 2, ch = off & 3;
            const char* src = (const char*)P + (((size_t)(r0_ + row) * K + i * 32) << 1)
                              + ((ch ^ (row & 3)) << 4);
            gload16(src, (char*)dst + off * 16);
        }
    };

    f32x4 acc[4][4] = {};
    issueT(Bt, col0, 0, Bs[0]);
    issueT(Aptr, row0, 0, As[0]);

    for (int i = 0; i < NI; i++) {
        const int p = i & 1;
        if (i + 1 < NI) {
            issueT(Bt, col0, i + 1, Bs[p ^ 1]);
            issueT(Aptr, row0, i + 1, As[p ^ 1]);
            VMWAIT(4);
        } else {
            VMWAIT(0);
        }
        barrier_();

        short8 af[4], bf_[4];
        #pragma unroll
        for (int mm = 0; mm < 4; mm++) {
            int r = wr * 64 + mm * 16 + lc;
            af[mm] = *(const short8*)((const char*)As[p] + r * 64 + ((lr * 16) ^ ((r & 3) << 4)));
        }
        #pragma unroll
        for (int nn = 0; nn < 4; nn++) {
            int r = wc * 64 + nn * 16 + lc;
            bf_[nn] = *(const short8*)((const char*)Bs[p] + r * 64 + ((lr * 16) ^ ((r & 3) << 4)));
        }
        #pragma unroll
        for (int mm = 0; mm < 4; mm++)
            #pragma unroll
            for (int nn = 0; nn < 4; nn++)
                acc[mm][nn] = __builtin_amdgcn_mfma_f32_16x16x32_bf16(af[mm], bf_[nn], acc[mm][nn], 0, 0, 0);
        __builtin_amdgcn_s_barrier();
    }

    float bv[4];
    #pragma unroll
    for (int nn = 0; nn < 4; nn++) bv[nn] = bias[col0 + wc * 64 + nn * 16 + lc];

    #pragma unroll
    for (int mm = 0; mm < 4; mm++) {
        const int row = row0 + wr * 64 + mm * 16 + lr * 4;
        #pragma unroll
        for (int nn = 0; nn < 4; nn++) {
            const int col = col0 + wc * 64 + nn * 16 + lc;
            #pragma unroll
            for (int r = 0; r < 4; r++)
                Cptr[(size_t)(row + r) * N + col] = acc[mm][nn][r] + bv[nn];
        }
    }
}

// ---------------------------------------------------------------------------
// Fused attention (R15, measured best): swapped QK^T, P in regs,
// counted-vmcnt 2-barrier pipeline, cvtpk, setprio, and COALESCED P-store
// via per-wave 16x32 f32 LDS transpose tiles (8 rows x 128B full lines).
// Q frags direct from global; LDS = 32+32+16 = 80KB -> 2 blocks/CU.
// ---------------------------------------------------------------------------
__global__ __launch_bounds__(512, 4)
void attn_kernel(const u16* __restrict__ qp, const u16* __restrict__ kp,
                 const u16* __restrict__ vt, float* __restrict__ Pout,
                 u16* __restrict__ xout)
{
    __shared__ __align__(16) u16 Ks[2][128 * 64];   // 32KB [k][d], source-swizzled
    __shared__ __align__(16) u16 Vts[2][64 * 128];  // 32KB [d][k] rows 256B, source-swizzled
    __shared__ __align__(16) float Pls[8][16][32];  // 16KB per-wave P transpose tiles

    const int t = threadIdx.x;
    const int w = t >> 6, l = t & 63, lr = l >> 4, lc = l & 15;
    // XCD-bijective swizzle: 512 blocks -> 8 chunks of 64 (= 4 bh each)
    const int bid = blockIdx.x;
    const int s = ((bid & 7) << 6) | (bid >> 3);
    const int q0 = (s & 15) * 128;
    const int bh = s >> 4, b = bh >> 4, h = bh & 15;
    const float L2E = 1.4426950408889634f;
    constexpr int NT = S_ / 128;                    // 16 tiles

    auto issueK = [&](int kt, int buf) {
        #pragma unroll
        for (int i = 0; i < 2; i++) {
            int off = i * 512 + t, row = off >> 3, ch = off & 7;
            const char* src = (const char*)kp + ((((size_t)b * S_ + kt * 128 + row) * D_ + h * 64) << 1)
                              + ((ch ^ (row & 7)) << 4);
            gload16(src, (char*)Ks[buf] + off * 16);
        }
    };
    auto issueV = [&](int kt, int buf) {
        #pragma unroll
        for (int i = 0; i < 2; i++) {
            int off = i * 512 + t, row = off >> 4, ch = off & 15;
            const char* src = (const char*)vt + ((((size_t)bh * 64 + row) * S_ + kt * 128) << 1)
                              + ((ch ^ (row & 7)) << 4);
            gload16(src, (char*)Vts[buf] + off * 16);
        }
    };

    issueK(0, 0);
    // Q frags direct from global
    short8 qf[2];
    {
        const u16* qrow = qp + ((size_t)b * S_ + q0 + w * 16 + lc) * D_ + h * 64;
        qf[0] = *(const short8*)(qrow + lr * 8);
        qf[1] = *(const short8*)(qrow + 32 + lr * 8);
    }

    // ---------------- pass 1: per-lane sum of exp(s) over own k-slice ----------------
    float sum = 0.f;
    for (int kt = 0; kt < NT; kt++) {
        const int p = kt & 1;
        if (kt + 1 < NT) { issueK(kt + 1, p ^ 1); VMWAIT(2); }
        else             { VMWAIT(0); }
        barrier_();
        const char* Kb = (const char*)Ks[p];
        #pragma unroll
        for (int f = 0; f < 8; f++) {
            int r = f * 16 + lc, sw = (r & 7) << 4;
            const char* kb = Kb + r * 128;
            short8 k0 = *(const short8*)(kb + ((lr * 16) ^ sw));
            short8 k1 = *(const short8*)(kb + ((64 + lr * 16) ^ sw));
            f32x4 sacc = {};
            sacc = __builtin_amdgcn_mfma_f32_16x16x32_bf16(k0, qf[0], sacc, 0, 0, 0);
            sacc = __builtin_amdgcn_mfma_f32_16x16x32_bf16(k1, qf[1], sacc, 0, 0, 0);
            sum += exp2f(sacc[0] * L2E) + exp2f(sacc[1] * L2E)
                 + exp2f(sacc[2] * L2E) + exp2f(sacc[3] * L2E);
        }
        __builtin_amdgcn_s_barrier();               // reads of buf p done before overwrite
    }
    issueK(0, 0); issueV(0, 0);                     // prefetch pass-2 tile 0 under the reduce
    sum += __shfl_xor(sum, 16);
    sum += __shfl_xor(sum, 32);
    const float l2i = -log2f(sum);                  // row-uniform; folded into exponent

    // ---------------- pass 2: P -> LDS transpose -> coalesced Pout + in-register PV ----------------
    f32x4 xacc[4] = {};
    float* pls = &Pls[w][0][0];
    float* prow0 = Pout + ((size_t)bh * S_ + q0 + w * 16) * S_;

    for (int kt = 0; kt < NT; kt++) {
        const int p = kt & 1;
        if (kt + 1 < NT) { issueK(kt + 1, p ^ 1); issueV(kt + 1, p ^ 1); }
        // vmcnt queue (old->new): [loads(kt) 4 | stores(kt-1) 8 | loads(kt+1) 4]
        if (kt == 0)           VMWAIT(4);
        else if (kt + 1 < NT)  VMWAIT(12);
        else                   VMWAIT(8);
        barrier_();
        const char* Kb = (const char*)Ks[p];
        const char* Vb = (const char*)Vts[p];

        #pragma unroll
        for (int kk = 0; kk < 4; kk++) {
            union { unsigned u[4]; short8 s8; } pu;
            #pragma unroll
            for (int fo = 0; fo < 2; fo++) {
                const int f = kk * 2 + fo;
                int r = f * 16 + lc, sw = (r & 7) << 4;
                const char* kb = Kb + r * 128;
                short8 k0 = *(const short8*)(kb + ((lr * 16) ^ sw));
                short8 k1 = *(const short8*)(kb + ((64 + lr * 16) ^ sw));
                f32x4 sacc = {};
                __builtin_amdgcn_s_setprio(1);
                sacc = __builtin_amdgcn_mfma_f32_16x16x32_bf16(k0, qf[0], sacc, 0, 0, 0);
                sacc = __builtin_amdgcn_mfma_f32_16x16x32_bf16(k1, qf[1], sacc, 0, 0, 0);
                __builtin_amdgcn_s_setprio(0);
                f32x4 pv_;
                pv_[0] = exp2f(fmaf(sacc[0], L2E, l2i));
                pv_[1] = exp2f(fmaf(sacc[1], L2E, l2i));
                pv_[2] = exp2f(fmaf(sacc[2], L2E, l2i));
                pv_[3] = exp2f(fmaf(sacc[3], L2E, l2i));
                // stage into per-wave transpose tile (row=lc, chunk=fo*4+lr, XOR-swizzled)
                *(f32x4*)((char*)pls + lc * 128 + (((fo * 64 + lr * 16)) ^ ((lc & 7) << 4))) = pv_;
                pu.u[fo * 2 + 0] = cvtpk(pv_[0], pv_[1]);
                pu.u[fo * 2 + 1] = cvtpk(pv_[2], pv_[3]);
            }
            // coalesced Pout store: 2 instructions x (8 rows x 128B full lines)
            {
                float* prow = prow0 + (size_t)kt * 128 + kk * 32;
                #pragma unroll
                for (int half = 0; half < 2; half++) {
                    int row = half * 8 + (l >> 3), chunk = l & 7;
                    f32x4 pr = *(const f32x4*)((const char*)pls + row * 128
                               + ((chunk * 16) ^ (((l >> 3) & 7) << 4)));
                    *(f32x4*)(prow + (size_t)row * S_ + chunk * 4) = pr;
                }
            }
            const short8 pa = pu.s8;   // A-frag: P[q=lc][k = kk*32 + perm(lr,j)]
            __builtin_amdgcn_s_setprio(1);
            #pragma unroll
            for (int n = 0; n < 4; n++) {
                int rr = n * 16 + lc, sw2 = (rr & 7) << 4;
                const char* vrow = Vb + rr * 256;
                union { bfx4 h[2]; short8 s8; } vu;
                vu.h[0] = *(const bfx4*)(vrow + ((kk * 64 + lr * 8) ^ sw2));
                vu.h[1] = *(const bfx4*)(vrow + ((kk * 64 + 32 + lr * 8) ^ sw2));
                xacc[n] = __builtin_amdgcn_mfma_f32_16x16x32_bf16(pa, vu.s8, xacc[n], 0, 0, 0);
            }
            __builtin_amdgcn_s_setprio(0);
        }
        __builtin_amdgcn_s_barrier();               // reads of buf p done before overwrite
    }

    #pragma unroll
    for (int n = 0; n < 4; n++) {
        #pragma unroll
        for (int r = 0; r < 4; r++) {
            int row = q0 + w * 16 + lr * 4 + r;
            int col = h * 64 + n * 16 + lc;
            xout[((size_t)b * S_ + row) * D_ + col] = f2bf(xacc[n][r]);
        }
    }
}

// ---------------------------------------------------------------------------
extern "C" void kernel_launch(void* const* d_in, const int* in_sizes, int n_in,
                              void* d_out, int out_size, void* d_ws, size_t ws_size,
                              hipStream_t stream)
{
    const float* qin = (const float*)d_in[0];
    const float* kin = (const float*)d_in[1];
    const float* vin = (const float*)d_in[2];
    const float* Wq  = (const float*)d_in[3];
    const float* bq  = (const float*)d_in[4];
    const float* Wk  = (const float*)d_in[5];
    const float* bk  = (const float*)d_in[6];
    const float* Wv  = (const float*)d_in[7];
    const float* bv  = (const float*)d_in[8];
    const float* Wo  = (const float*)d_in[9];
    const float* bo  = (const float*)d_in[10];

    // ws layout (u16 elements)
    u16* base = (u16*)d_ws;
    u16* Wqt = base;                    // 1M each
    u16* Wkt = base + 1048576;
    u16* Wvt = base + 2097152;
    u16* Wot = base + 3145728;
    u16* qpb = base + 4194304;          // 4M each
    u16* kpb = base + 8388608;
    u16* vpb = base + 12582912;
    u16* vtb = base + 16777216;         // vt[bh][64][2048]
    u16* xb  = base + 20971520;         // total ~50MB

    float* out  = (float*)d_out;
    float* Pout = out + OUT_ELEMS;

    wtrans_kernel<<<dim3(16, 16, 4), 256, 0, stream>>>(Wq, Wk, Wv, Wo, Wqt, Wkt, Wvt, Wot);
    gemm_qkvf<<<dim3(8, 32, 3), 256, 0, stream>>>(
        qin, kin, vin, Wqt, Wkt, Wvt, bq, bk, bv, qpb, kpb, vpb);
    vtrans_kernel<<<dim3(32, 32), 256, 0, stream>>>(vpb, vtb);
    attn_kernel<<<512, 512, 0, stream>>>(qpb, kpb, vtb, Pout, xb);
    gemm_out<<<dim3(8, 32), 256, 0, stream>>>(xb, Wot, bo, out);
}